// Round 4
// baseline (291.123 us; speedup 1.0000x reference)
//
#include <hip/hip_runtime.h>

#define BATCH 8
#define CH 128
#define HH 128
#define WW 128
#define HWSZ 16384
#define NHEADS 8
#define DHEAD 2048

typedef short bf16x8 __attribute__((ext_vector_type(8)));
typedef short bf16x4v __attribute__((ext_vector_type(4)));
typedef float f32x4 __attribute__((ext_vector_type(4)));
typedef float f32x2 __attribute__((ext_vector_type(2)));
typedef _Float16 f16x8 __attribute__((ext_vector_type(8)));
typedef _Float16 f16x4 __attribute__((ext_vector_type(4)));

static __device__ inline unsigned short f2bf(float f) {
    unsigned u = __builtin_bit_cast(unsigned, f);
    u += 0x7fff + ((u >> 16) & 1);          // round-to-nearest-even
    return (unsigned short)(u >> 16);
}

// ---------------- Kernel 0: build Toeplitz fragments for dwconv MFMA ----------
// Layout is valid as either A-operand (i=lane&15) or B-operand (j=lane&15):
// value[k=(lane>>4)*8+e] = w[dy*9 + (k - (lane&15))] for diff in [0,8].
__global__ __launch_bounds__(256) void toeplitz_prep_kernel(
    const float* __restrict__ wq, const float* __restrict__ wk,
    const float* __restrict__ wv, _Float16* __restrict__ Tp)
{
    const int g = blockIdx.x * 256 + threadIdx.x;   // 128*27*64 = 221184
    const int c    = g / 1728;                      // 27*64
    const int rem  = g - c * 1728;
    const int m    = rem >> 6;
    const int lane = rem & 63;
    const int conv = m / 9;
    const int dy   = m - conv * 9;
    const float* w = (conv == 0) ? wq : ((conv == 1) ? wk : wv);
    const int j    = lane & 15;
    const int kb   = (lane >> 4) << 3;
    f16x8 h;
    #pragma unroll
    for (int e = 0; e < 8; ++e) {
        const int d = kb + e - j;
        h[e] = (d >= 0 && d <= 8) ? (_Float16)w[c * 81 + dy * 9 + d]
                                  : (_Float16)0.f;
    }
    *(f16x8*)&Tp[(size_t)g * 8] = h;
}

// ---------------- Kernel 1: depthwise 9x9 conv -> Q,K,V via MFMA Toeplitz -----
// A-operand = Toeplitz (i = output x), B-operand = image (j = y). Lane then
// holds 4 x-consecutive outputs -> bf16x4 stores (6 per t-iter vs 24 scalar).
__global__ __launch_bounds__(256) void dwconv_qkv_mfma_kernel(
    const float* __restrict__ x,
    const float* __restrict__ bq, const float* __restrict__ bk,
    const float* __restrict__ bv,
    const _Float16* __restrict__ Tp,
    unsigned short* __restrict__ Qb, unsigned short* __restrict__ Kb,
    unsigned short* __restrict__ Vb)
{
    const int bc = blockIdx.x;
    const int b  = bc >> 7;
    const int c  = bc & (CH - 1);

    __shared__ _Float16 img[136][144];   // [y+4][x+4], zero halo, 39168 B

    const int tid  = threadIdx.x;
    const int wave = tid >> 6;
    const int lane = tid & 63;
    const int lx   = lane & 15;
    const int qd   = lane >> 4;

    f16x8 Btp[27];
    const _Float16* tp = Tp + (size_t)c * 13824 + (size_t)lane * 8;
    #pragma unroll
    for (int m = 0; m < 27; ++m)
        Btp[m] = *(const f16x8*)(tp + (size_t)m * 512);

    {
        f16x8 z = {0, 0, 0, 0, 0, 0, 0, 0};
        _Float16* flat = &img[0][0];
        for (int i = tid; i < 2448; i += 256)       // 136*144/8
            *(f16x8*)&flat[i * 8] = z;
    }
    __syncthreads();
    const float* xp = x + (size_t)bc * HWSZ;
    for (int i = tid; i < 4096; i += 256) {
        const float4 v = *(const float4*)&xp[i * 4];
        const int y  = i >> 5;
        const int xc = (i & 31) << 2;
        f16x4 h = {(_Float16)v.x, (_Float16)v.y, (_Float16)v.z, (_Float16)v.w};
        *(f16x4*)&img[y + 4][xc + 4] = h;
    }
    __syncthreads();

    const float bqv = bq[c], bkv = bk[c], bvv = bv[c];

    #pragma unroll 1
    for (int t = 0; t < 8; ++t) {
        const int sg = t * 4 + wave;                // 32 supergroups / block
        const int yg = sg >> 2;
        const int y0 = yg << 4;
        const int x0 = (sg & 3) << 5;

        f32x4 aq0 = {bqv, bqv, bqv, bqv}, aq1 = aq0;
        f32x4 ak0 = {bkv, bkv, bkv, bkv}, ak1 = ak0;
        f32x4 av0 = {bvv, bvv, bvv, bvv}, av1 = av0;

        const _Float16* rp = &img[y0 + lx][x0 + (qd << 3)];
        #pragma unroll
        for (int dy = 0; dy < 9; ++dy) {
            const f16x8 a0 = *(const f16x8*)rp;
            const f16x8 a1 = *(const f16x8*)(rp + 16);
            rp += 144;
            aq0 = __builtin_amdgcn_mfma_f32_16x16x32_f16(Btp[dy],      a0, aq0, 0, 0, 0);
            aq1 = __builtin_amdgcn_mfma_f32_16x16x32_f16(Btp[dy],      a1, aq1, 0, 0, 0);
            ak0 = __builtin_amdgcn_mfma_f32_16x16x32_f16(Btp[9 + dy],  a0, ak0, 0, 0, 0);
            ak1 = __builtin_amdgcn_mfma_f32_16x16x32_f16(Btp[9 + dy],  a1, ak1, 0, 0, 0);
            av0 = __builtin_amdgcn_mfma_f32_16x16x32_f16(Btp[18 + dy], a0, av0, 0, 0, 0);
            av1 = __builtin_amdgcn_mfma_f32_16x16x32_f16(Btp[18 + dy], a1, av1, 0, 0, 0);
        }

        // D[i=xout][j=y]: lane holds x = x0 + qd*4 + r (r=0..3), y = y0 + lx
        const size_t base = ((size_t)(b * 8 + yg) * CH + c) * DHEAD
                          + (size_t)lx * WW + x0 + (qd << 2);
        bf16x4v h;
        h[0] = (short)f2bf(aq0[0]); h[1] = (short)f2bf(aq0[1]);
        h[2] = (short)f2bf(aq0[2]); h[3] = (short)f2bf(aq0[3]);
        *(bf16x4v*)&Qb[base] = h;
        h[0] = (short)f2bf(aq1[0]); h[1] = (short)f2bf(aq1[1]);
        h[2] = (short)f2bf(aq1[2]); h[3] = (short)f2bf(aq1[3]);
        *(bf16x4v*)&Qb[base + 16] = h;
        h[0] = (short)f2bf(ak0[0]); h[1] = (short)f2bf(ak0[1]);
        h[2] = (short)f2bf(ak0[2]); h[3] = (short)f2bf(ak0[3]);
        *(bf16x4v*)&Kb[base] = h;
        h[0] = (short)f2bf(ak1[0]); h[1] = (short)f2bf(ak1[1]);
        h[2] = (short)f2bf(ak1[2]); h[3] = (short)f2bf(ak1[3]);
        *(bf16x4v*)&Kb[base + 16] = h;
        h[0] = (short)f2bf(av0[0]); h[1] = (short)f2bf(av0[1]);
        h[2] = (short)f2bf(av0[2]); h[3] = (short)f2bf(av0[3]);
        *(bf16x4v*)&Vb[base] = h;
        h[0] = (short)f2bf(av1[0]); h[1] = (short)f2bf(av1[1]);
        h[2] = (short)f2bf(av1[2]); h[3] = (short)f2bf(av1[3]);
        *(bf16x4v*)&Vb[base + 16] = h;
    }
}

// ---------------- Kernel 2: fused S = QK^T (full t) + row softmax -> P bf16 ---
// Grid 256 = bh(64) x row-tile(4). Block computes 32 complete S-rows over
// t=2048 (16 chunks of 128), then softmaxes in-block. Spart eliminated.
__global__ __launch_bounds__(256) void qks_kernel(
    const unsigned short* __restrict__ Qb, const unsigned short* __restrict__ Kb,
    unsigned short* __restrict__ Pb)
{
    // XCD swizzle: 4 sibling blocks (same bh, sharing K) on one XCD
    const int blk = ((blockIdx.x & 7) << 5) | (blockIdx.x >> 3);
    const int bh  = blk >> 2;
    const int c0  = (blk & 3) << 5;

    __shared__ __align__(16) char smem[41216];   // Qs 8K | Ks 32K ; Ss overlays

    const int tid  = threadIdx.x;
    const int wave = tid >> 6;
    const int lane = tid & 63;
    const int lx   = lane & 15;
    const int qd   = lane >> 4;
    const int n0   = wave << 5;                  // col strip per wave

    f32x4 acc[2][2];
    #pragma unroll
    for (int mi = 0; mi < 2; ++mi)
        #pragma unroll
        for (int ni = 0; ni < 2; ++ni) acc[mi][ni] = (f32x4){0.f, 0.f, 0.f, 0.f};

    const unsigned short* Qp = Qb + ((size_t)bh * CH + c0) * DHEAD;
    const unsigned short* Kp = Kb + (size_t)bh * CH * DHEAD;

    #pragma unroll 1
    for (int chk = 0; chk < 16; ++chk) {
        const int t0 = chk << 7;
        __syncthreads();
        for (int i = tid; i < 512; i += 256) {          // Q: 32 rows x 16 units
            const int r = i >> 4, u = i & 15;
            const bf16x8 v = *(const bf16x8*)&Qp[(size_t)r * DHEAD + t0 + u * 8];
            const unsigned off = (unsigned)((r << 8) + (u << 4)) ^ (((unsigned)r & 7u) << 4);
            *(bf16x8*)(smem + off) = v;
        }
        for (int i = tid; i < 2048; i += 256) {         // K: 128 rows x 16 units
            const int r = i >> 4, u = i & 15;
            const bf16x8 v = *(const bf16x8*)&Kp[(size_t)r * DHEAD + t0 + u * 8];
            const unsigned off = 8192u + ((unsigned)((r << 8) + (u << 4)) ^ (((unsigned)r & 7u) << 4));
            *(bf16x8*)(smem + off) = v;
        }
        __syncthreads();
        #pragma unroll
        for (int ki = 0; ki < 4; ++ki) {
            const int kc = ki * 32 + qd * 8;
            bf16x8 a[2], bv[2];
            #pragma unroll
            for (int mi = 0; mi < 2; ++mi) {
                const int r = mi * 16 + lx;
                a[mi] = *(const bf16x8*)(smem +
                        ((unsigned)((r << 8) + (kc << 1)) ^ (((unsigned)r & 7u) << 4)));
            }
            #pragma unroll
            for (int ni = 0; ni < 2; ++ni) {
                const int r = n0 + ni * 16 + lx;
                bv[ni] = *(const bf16x8*)(smem + 8192u +
                        ((unsigned)((r << 8) + (kc << 1)) ^ (((unsigned)r & 7u) << 4)));
            }
            #pragma unroll
            for (int mi = 0; mi < 2; ++mi)
                #pragma unroll
                for (int ni = 0; ni < 2; ++ni)
                    acc[mi][ni] = __builtin_amdgcn_mfma_f32_16x16x32_bf16(
                        a[mi], bv[ni], acc[mi][ni], 0, 0, 0);
        }
    }

    __syncthreads();
    float* Ss = (float*)smem;                    // [32][132] f32, 16896 B
    #pragma unroll
    for (int mi = 0; mi < 2; ++mi)
        #pragma unroll
        for (int ni = 0; ni < 2; ++ni)
            #pragma unroll
            for (int r = 0; r < 4; ++r)
                Ss[(mi * 16 + qd * 4 + r) * 132 + n0 + ni * 16 + lx] = acc[mi][ni][r];
    __syncthreads();

    // softmax: 8 threads per row, 16 cols each
    const int rr   = tid >> 3;
    const int col0 = (tid & 7) << 4;
    f32x4 v0 = *(const f32x4*)&Ss[rr * 132 + col0];
    f32x4 v1 = *(const f32x4*)&Ss[rr * 132 + col0 + 4];
    f32x4 v2 = *(const f32x4*)&Ss[rr * 132 + col0 + 8];
    f32x4 v3 = *(const f32x4*)&Ss[rr * 132 + col0 + 12];
    const f32x4 sc = {0.0078125f, 0.0078125f, 0.0078125f, 0.0078125f};
    v0 *= sc; v1 *= sc; v2 *= sc; v3 *= sc;
    float m = v0[0];
    #pragma unroll
    for (int j = 1; j < 4; ++j) m = fmaxf(m, v0[j]);
    #pragma unroll
    for (int j = 0; j < 4; ++j) { m = fmaxf(m, v1[j]); m = fmaxf(m, v2[j]); m = fmaxf(m, v3[j]); }
    m = fmaxf(m, __shfl_xor(m, 1));
    m = fmaxf(m, __shfl_xor(m, 2));
    m = fmaxf(m, __shfl_xor(m, 4));
    float e[16];
    #pragma unroll
    for (int j = 0; j < 4; ++j) {
        e[j]      = __expf(v0[j] - m);
        e[4 + j]  = __expf(v1[j] - m);
        e[8 + j]  = __expf(v2[j] - m);
        e[12 + j] = __expf(v3[j] - m);
    }
    float s = 0.f;
    #pragma unroll
    for (int j = 0; j < 16; ++j) s += e[j];
    s += __shfl_xor(s, 1);
    s += __shfl_xor(s, 2);
    s += __shfl_xor(s, 4);
    const float inv = 1.f / s;
    bf16x8 h0, h1;
    #pragma unroll
    for (int j = 0; j < 8; ++j) {
        h0[j] = (short)f2bf(e[j] * inv);
        h1[j] = (short)f2bf(e[8 + j] * inv);
    }
    unsigned short* prow = Pb + ((size_t)bh * CH + c0 + rr) * CH + col0;
    *(bf16x8*)&prow[0] = h0;
    *(bf16x8*)&prow[8] = h1;
}

// ---------------- Kernel 4: A = P V via MFMA, out At[b][p][ci] bf16 ------------
__global__ __launch_bounds__(256) void pv_mfma_kernel(
    const unsigned short* __restrict__ Pb, const unsigned short* __restrict__ Vb,
    unsigned short* __restrict__ At)
{
    const int blk = blockIdx.x;
    const int t0  = (blk & 15) << 7;
    const int bh  = blk >> 4;

    __shared__ __align__(16) char smem[69632];
    unsigned short (*Ps)[136] = (unsigned short(*)[136])smem;            // 34816 B
    unsigned short (*Vs)[136] = (unsigned short(*)[136])(smem + 34816);  // 34816 B
    float (*So)[132] = (float(*)[132])smem;                              // reused

    const int tid  = threadIdx.x;
    const int wave = tid >> 6;
    const int lane = tid & 63;
    const int lx   = lane & 15;
    const int qd   = lane >> 4;
    const int m0   = (wave & 1) * 64;      // c tile
    const int n0   = (wave >> 1) * 64;     // t tile

    const unsigned short* Pp = Pb + (size_t)bh * CH * CH;
    const unsigned short* Vp = Vb + (size_t)bh * CH * DHEAD;

    for (int i = tid; i < 2048; i += 256) {
        const int r  = i >> 4;
        const int cl = (i & 15) << 3;
        *(bf16x8*)&Ps[r][cl] = *(const bf16x8*)&Pp[(size_t)r * CH + cl];
    }
    for (int i = tid; i < 2048; i += 256) {
        const int e   = i & 127;
        const int tc8 = (i >> 7) << 3;
        const bf16x8 vv = *(const bf16x8*)&Vp[(size_t)e * DHEAD + t0 + tc8];
        #pragma unroll
        for (int j = 0; j < 8; ++j) Vs[tc8 + j][e] = (unsigned short)vv[j];
    }
    __syncthreads();

    f32x4 acc[4][4];
    #pragma unroll
    for (int mi = 0; mi < 4; ++mi)
        #pragma unroll
        for (int ni = 0; ni < 4; ++ni) acc[mi][ni] = (f32x4){0.f, 0.f, 0.f, 0.f};

    #pragma unroll
    for (int ki = 0; ki < 4; ++ki) {
        const int kc = ki * 32 + qd * 8;
        bf16x8 a[4], bv[4];
        #pragma unroll
        for (int mi = 0; mi < 4; ++mi)
            a[mi] = *(const bf16x8*)&Ps[m0 + mi * 16 + lx][kc];
        #pragma unroll
        for (int ni = 0; ni < 4; ++ni)
            bv[ni] = *(const bf16x8*)&Vs[n0 + ni * 16 + lx][kc];
        #pragma unroll
        for (int mi = 0; mi < 4; ++mi)
            #pragma unroll
            for (int ni = 0; ni < 4; ++ni)
                acc[mi][ni] = __builtin_amdgcn_mfma_f32_16x16x32_bf16(
                    a[mi], bv[ni], acc[mi][ni], 0, 0, 0);
    }

    __syncthreads();
    #pragma unroll
    for (int mi = 0; mi < 4; ++mi)
        #pragma unroll
        for (int ni = 0; ni < 4; ++ni)
            #pragma unroll
            for (int r = 0; r < 4; ++r)
                So[n0 + ni * 16 + lx][m0 + mi * 16 + qd * 4 + r] = acc[mi][ni][r];
    __syncthreads();

    const int t  = tid >> 1;
    const int ch = (tid & 1) * 64;
    const size_t orow = (((size_t)(bh >> 3) * HWSZ) + (size_t)(bh & 7) * DHEAD + t0 + t) * CH + ch;
    #pragma unroll
    for (int j = 0; j < 8; ++j) {
        const float4 f0 = *(const float4*)&So[t][ch + j * 8];
        const float4 f1 = *(const float4*)&So[t][ch + j * 8 + 4];
        bf16x8 h;
        h[0] = (short)f2bf(f0.x); h[1] = (short)f2bf(f0.y);
        h[2] = (short)f2bf(f0.z); h[3] = (short)f2bf(f0.w);
        h[4] = (short)f2bf(f1.x); h[5] = (short)f2bf(f1.y);
        h[6] = (short)f2bf(f1.z); h[7] = (short)f2bf(f1.w);
        *(bf16x8*)&At[orow + j * 8] = h;
    }
}

// ---------------- Kernel 5a: weight prep wo fp32 -> Wt[tap][co][ci] bf16 ------
__global__ __launch_bounds__(256) void wprep_kernel(
    const float* __restrict__ wo, unsigned short* __restrict__ Wt)
{
    const int i = blockIdx.x * 256 + threadIdx.x;     // 9*128*128 = 147456
    const int tap = i >> 14;
    const int rem = i & 16383;
    const int co  = rem >> 7;
    const int ci  = rem & 127;
    Wt[i] = f2bf(wo[(size_t)(co * CH + ci) * 9 + tap]);
}

// ---------------- Kernel 5b: 3x3 dense conv, 2-row blocks ---------------------
// sA [4][128 x][256B] (no halo cols; edge frags clamp+zero), double-buffered
// sW[2][16KB] -> exactly 160 KiB LDS, ONE barrier per phase (18 total).
__global__ __launch_bounds__(512, 2) void conv3x3_mfma_kernel(
    const unsigned short* __restrict__ At, const unsigned short* __restrict__ Wt,
    const float* __restrict__ bo, float* __restrict__ out)
{
    __shared__ __align__(16) char smem[163840];   // sA 131072 + sW 2x16384

    const int w    = ((blockIdx.x & 7) << 6) | (blockIdx.x >> 3);
    const int yp   = w & 63;
    const int b    = w >> 6;
    const int y0   = yp << 1;

    const int tid  = threadIdx.x;
    const int wave = tid >> 6;
    const int lane = tid & 63;
    const int lx   = lane & 15;
    const int qd   = lane >> 4;
    const int m0   = (wave & 1) << 6;       // co half
    const int n0   = (wave >> 1) << 6;      // px quarter
    const int rsel = n0 >> 7;               // output row within pair (0/1)
    const int xb   = n0 & 64;               // x base within row

    const int j0 = tid, j1 = tid + 512;     // weight 16B-unit indices (0..1023)
    const int co0 = j0 >> 3, cu0 = j0 & 7;
    const int co1 = j1 >> 3, cu1 = j1 & 7;
    const unsigned swo0 = (unsigned)((co0 * 128 + cu0 * 16) ^ ((co0 & 7) << 4)) + 131072u;
    const unsigned swo1 = (unsigned)((co1 * 128 + cu1 * 16) ^ ((co1 & 7) << 4)) + 131072u;

    // prologue: issue slice-0 weight loads (tap0, kh0)
    float4 nwa = *(const float4*)&Wt[(size_t)co0 * 128 + cu0 * 8];
    float4 nwb = *(const float4*)&Wt[(size_t)co1 * 128 + cu1 * 8];

    // stage sA: 4 input rows, x = 0..127 (no halo cols), zero OOB rows
    const size_t abase = (size_t)b * HWSZ * CH;
    for (int i = tid; i < 8192; i += 512) {
        const int r   = i >> 11;
        const int rem = i & 2047;
        const int xx  = rem >> 4;               // 0..127
        const int u   = rem & 15;
        const int gy  = y0 - 1 + r;
        float4 v = make_float4(0.f, 0.f, 0.f, 0.f);
        if ((unsigned)gy < HH)
            v = *(const float4*)&At[abase + (size_t)gy * WW * CH + xx * CH + u * 8];
        const int xp = xx + 1;
        const unsigned off = (unsigned)((r << 15) + (xx << 8) + (u << 4))
                           ^ (((unsigned)xp & 7u) << 4);
        *(float4*)(smem + off) = v;
    }
    // write slice 0 to buf0, then issue slice-1 loads (tap0, kh1)
    *(float4*)(smem + swo0) = nwa;
    *(float4*)(smem + swo1) = nwb;
    nwa = *(const float4*)&Wt[(size_t)co0 * 128 + 64 + cu0 * 8];
    nwb = *(const float4*)&Wt[(size_t)co1 * 128 + 64 + cu1 * 8];

    f32x4 acc[4][4];
    #pragma unroll
    for (int mi = 0; mi < 4; ++mi) {
        f32x4 bv;
        #pragma unroll
        for (int r = 0; r < 4; ++r) bv[r] = bo[m0 + mi * 16 + qd * 4 + r];
        #pragma unroll
        for (int ni = 0; ni < 4; ++ni) acc[mi][ni] = bv;
    }

    __syncthreads();

    #pragma unroll 1
    for (int s = 0; s < 18; ++s) {
        const int tap = s >> 1;
        const int dy  = (tap * 11) >> 5;        // tap/3
        const int txc = tap - dy * 3;           // tap%3
        const int kh  = s & 1;
        const int ra  = rsel + dy;
        const unsigned wbase = 131072u + (unsigned)(s & 1) * 16384u;

        #pragma unroll
        for (int ks = 0; ks < 2; ++ks) {
            const int wkb = ks * 64 + qd * 16;            // ci-byte in sW slice
            const int akb = kh * 128 + ks * 64 + qd * 16; // ci-byte in sA row
            bf16x8 a[4], bfr[4];
            #pragma unroll
            for (int mi = 0; mi < 4; ++mi) {
                const int co = m0 + mi * 16 + lx;
                a[mi] = *(const bf16x8*)(smem + wbase +
                        (unsigned)((co * 128 + wkb) ^ ((co & 7) << 4)));
            }
            #pragma unroll
            for (int ni = 0; ni < 4; ++ni) {
                const int xp = xb + ni * 16 + lx + txc;   // 0..129
                const bool z = (unsigned)(xp - 1) >= 128u;
                const int xpc = z ? 1 : xp;
                const unsigned off = (unsigned)((ra << 15) + ((xpc - 1) << 8) + akb)
                                   ^ (((unsigned)xpc & 7u) << 4);
                bfr[ni] = *(const bf16x8*)(smem + off);
                if (z) bfr[ni] = (bf16x8){0, 0, 0, 0, 0, 0, 0, 0};
            }
            #pragma unroll
            for (int mi = 0; mi < 4; ++mi)
                #pragma unroll
                for (int ni = 0; ni < 4; ++ni)
                    acc[mi][ni] = __builtin_amdgcn_mfma_f32_16x16x32_bf16(
                        a[mi], bfr[ni], acc[mi][ni], 0, 0, 0);
        }
        if (s < 17) {
            const unsigned nb = 131072u + (unsigned)((s + 1) & 1) * 16384u;
            *(float4*)(smem + (swo0 - 131072u) + nb) = nwa;
            *(float4*)(smem + (swo1 - 131072u) + nb) = nwb;
            if (s < 16) {
                const int s2 = s + 2;
                const size_t gb = (size_t)(s2 >> 1) * 16384 + (s2 & 1) * 64;
                nwa = *(const float4*)&Wt[gb + co0 * 128 + cu0 * 8];
                nwb = *(const float4*)&Wt[gb + co1 * 128 + cu1 * 8];
            }
        }
        __syncthreads();
    }

    // epilogue: out[b][co][y0+rsel][x]
    const int gy = y0 + rsel;
    const size_t obase = (size_t)b * CH * HWSZ + (size_t)gy * WW + xb;
    #pragma unroll
    for (int mi = 0; mi < 4; ++mi) {
        #pragma unroll
        for (int r = 0; r < 4; ++r) {
            const int co = m0 + mi * 16 + qd * 4 + r;
            float* orow = out + obase + (size_t)co * HWSZ;
            #pragma unroll
            for (int ni = 0; ni < 4; ++ni)
                orow[ni * 16 + lx] = acc[mi][ni][r];
        }
    }
}

extern "C" void kernel_launch(void* const* d_in, const int* in_sizes, int n_in,
                              void* d_out, int out_size, void* d_ws, size_t ws_size,
                              hipStream_t stream)
{
    const float* x  = (const float*)d_in[0];
    const float* wq = (const float*)d_in[1];
    const float* bq = (const float*)d_in[2];
    const float* wk = (const float*)d_in[3];
    const float* bk = (const float*)d_in[4];
    const float* wv = (const float*)d_in[5];
    const float* bv = (const float*)d_in[6];
    const float* wo = (const float*)d_in[7];
    const float* bo = (const float*)d_in[8];

    char* ws = (char*)d_ws;
    unsigned short* Qb    = (unsigned short*)(ws);                        // 32 MiB
    unsigned short* Kb    = (unsigned short*)(ws + (size_t)33554432);     // 32 MiB
    unsigned short* Vb    = (unsigned short*)(ws + (size_t)67108864);     // 32 MiB
    unsigned short* Pb    = (unsigned short*)(ws + (size_t)134217728);    // 2 MiB
    unsigned short* At    = (unsigned short*)(ws + (size_t)136314880);    // 32 MiB
    unsigned short* Wt    = (unsigned short*)(ws + (size_t)169869312);    // 288 KiB
    _Float16*       Tp    = (_Float16*)      (ws + (size_t)100663296);    // 3.5 MiB (ex-Spart)

    toeplitz_prep_kernel<<<864, 256, 0, stream>>>(wq, wk, wv, Tp);
    dwconv_qkv_mfma_kernel<<<BATCH * CH, 256, 0, stream>>>(x, bq, bk, bv, Tp, Qb, Kb, Vb);
    wprep_kernel<<<576, 256, 0, stream>>>(wo, Wt);
    qks_kernel<<<256, 256, 0, stream>>>(Qb, Kb, Pb);
    pv_mfma_kernel<<<64 * 16, 256, 0, stream>>>(Pb, Vb, At);
    conv3x3_mfma_kernel<<<BATCH * 64, 512, 0, stream>>>(At, Wt, bo, (float*)d_out);
}

// Round 5
// 277.601 us; speedup vs baseline: 1.0487x; 1.0487x over previous
//
#include <hip/hip_runtime.h>

#define BATCH 8
#define CH 128
#define HH 128
#define WW 128
#define HWSZ 16384
#define NHEADS 8
#define DHEAD 2048

typedef short bf16x8 __attribute__((ext_vector_type(8)));
typedef short bf16x4v __attribute__((ext_vector_type(4)));
typedef float f32x4 __attribute__((ext_vector_type(4)));
typedef float f32x2 __attribute__((ext_vector_type(2)));
typedef _Float16 f16x8 __attribute__((ext_vector_type(8)));
typedef _Float16 f16x4 __attribute__((ext_vector_type(4)));

static __device__ inline unsigned short f2bf(float f) {
    unsigned u = __builtin_bit_cast(unsigned, f);
    u += 0x7fff + ((u >> 16) & 1);          // round-to-nearest-even
    return (unsigned short)(u >> 16);
}

// ---------------- Kernel 0: build Toeplitz fragments for dwconv MFMA ----------
__global__ __launch_bounds__(256) void toeplitz_prep_kernel(
    const float* __restrict__ wq, const float* __restrict__ wk,
    const float* __restrict__ wv, _Float16* __restrict__ Tp)
{
    const int g = blockIdx.x * 256 + threadIdx.x;   // 128*27*64 = 221184
    const int c    = g / 1728;                      // 27*64
    const int rem  = g - c * 1728;
    const int m    = rem >> 6;
    const int lane = rem & 63;
    const int conv = m / 9;
    const int dy   = m - conv * 9;
    const float* w = (conv == 0) ? wq : ((conv == 1) ? wk : wv);
    const int j    = lane & 15;
    const int kb   = (lane >> 4) << 3;
    f16x8 h;
    #pragma unroll
    for (int e = 0; e < 8; ++e) {
        const int d = kb + e - j;
        h[e] = (d >= 0 && d <= 8) ? (_Float16)w[c * 81 + dy * 9 + d]
                                  : (_Float16)0.f;
    }
    *(f16x8*)&Tp[(size_t)g * 8] = h;
}

// ---------------- Kernel 1: depthwise 9x9 conv -> Q,K,V via MFMA Toeplitz -----
// (round-3 body: A = image frags, B = Toeplitz; measured 58-63 us)
__global__ __launch_bounds__(256) void dwconv_qkv_mfma_kernel(
    const float* __restrict__ x,
    const float* __restrict__ bq, const float* __restrict__ bk,
    const float* __restrict__ bv,
    const _Float16* __restrict__ Tp,
    unsigned short* __restrict__ Qb, unsigned short* __restrict__ Kb,
    unsigned short* __restrict__ Vb)
{
    const int bc = blockIdx.x;
    const int b  = bc >> 7;
    const int c  = bc & (CH - 1);

    __shared__ _Float16 img[136][144];   // [y+4][x+4], zero halo, 39168 B

    const int tid  = threadIdx.x;
    const int wave = tid >> 6;
    const int lane = tid & 63;
    const int lx   = lane & 15;
    const int qd   = lane >> 4;

    f16x8 Btp[27];
    const _Float16* tp = Tp + (size_t)c * 13824 + (size_t)lane * 8;
    #pragma unroll
    for (int m = 0; m < 27; ++m)
        Btp[m] = *(const f16x8*)(tp + (size_t)m * 512);

    {
        f16x8 z = {0, 0, 0, 0, 0, 0, 0, 0};
        _Float16* flat = &img[0][0];
        for (int i = tid; i < 2448; i += 256)       // 136*144/8
            *(f16x8*)&flat[i * 8] = z;
    }
    __syncthreads();
    const float* xp = x + (size_t)bc * HWSZ;
    for (int i = tid; i < 4096; i += 256) {
        const float4 v = *(const float4*)&xp[i * 4];
        const int y  = i >> 5;
        const int xc = (i & 31) << 2;
        f16x4 h = {(_Float16)v.x, (_Float16)v.y, (_Float16)v.z, (_Float16)v.w};
        *(f16x4*)&img[y + 4][xc + 4] = h;
    }
    __syncthreads();

    const float bqv = bq[c], bkv = bk[c], bvv = bv[c];

    #pragma unroll 1
    for (int t = 0; t < 8; ++t) {
        const int sg = t * 4 + wave;                // 32 supergroups / block
        const int yg = sg >> 2;
        const int y0 = yg << 4;
        const int x0 = (sg & 3) << 5;

        f32x4 aq0 = {bqv, bqv, bqv, bqv}, aq1 = aq0;
        f32x4 ak0 = {bkv, bkv, bkv, bkv}, ak1 = ak0;
        f32x4 av0 = {bvv, bvv, bvv, bvv}, av1 = av0;

        const _Float16* rp = &img[y0 + lx][x0 + (qd << 3)];
        #pragma unroll
        for (int dy = 0; dy < 9; ++dy) {
            const f16x8 a0 = *(const f16x8*)rp;
            const f16x8 a1 = *(const f16x8*)(rp + 16);
            rp += 144;
            aq0 = __builtin_amdgcn_mfma_f32_16x16x32_f16(a0, Btp[dy],      aq0, 0, 0, 0);
            aq1 = __builtin_amdgcn_mfma_f32_16x16x32_f16(a1, Btp[dy],      aq1, 0, 0, 0);
            ak0 = __builtin_amdgcn_mfma_f32_16x16x32_f16(a0, Btp[9 + dy],  ak0, 0, 0, 0);
            ak1 = __builtin_amdgcn_mfma_f32_16x16x32_f16(a1, Btp[9 + dy],  ak1, 0, 0, 0);
            av0 = __builtin_amdgcn_mfma_f32_16x16x32_f16(a0, Btp[18 + dy], av0, 0, 0, 0);
            av1 = __builtin_amdgcn_mfma_f32_16x16x32_f16(a1, Btp[18 + dy], av1, 0, 0, 0);
        }

        // C layout: lane holds D[y = qd*4+r][x = lx]; t = (y&15)*128 + x, head = yg
        const size_t base = ((size_t)(b * 8 + yg) * CH + c) * DHEAD
                          + (size_t)(qd << 2) * WW + x0 + lx;
        #pragma unroll
        for (int r = 0; r < 4; ++r) {
            Qb[base + r * WW]      = f2bf(aq0[r]);
            Qb[base + r * WW + 16] = f2bf(aq1[r]);
            Kb[base + r * WW]      = f2bf(ak0[r]);
            Kb[base + r * WW + 16] = f2bf(ak1[r]);
            Vb[base + r * WW]      = f2bf(av0[r]);
            Vb[base + r * WW + 16] = f2bf(av1[r]);
        }
    }
}

// ---------------- Kernel 2: fused S = QK^T (full t) + row softmax -> P bf16 ---
// Grid 512 = row-tile(8, 16 rows each) x bh(64); o&63 = bh so a bh's 8 tiles
// land on one XCD (round-robin %8) -> K restage is L2-local. LDS 36 KB ->
// 4 blocks/CU (the round-4 version's 1 block/CU was the latency trap).
__global__ __launch_bounds__(256) void qks_kernel(
    const unsigned short* __restrict__ Qb, const unsigned short* __restrict__ Kb,
    unsigned short* __restrict__ Pb)
{
    const int o    = blockIdx.x;
    const int bh   = o & 63;
    const int c0   = (o >> 6) << 4;              // 16-row tile

    __shared__ __align__(16) char smem[36864];   // Qs 4K | Ks 32K ; Ss overlays

    const int tid  = threadIdx.x;
    const int wave = tid >> 6;
    const int lane = tid & 63;
    const int lx   = lane & 15;
    const int qd   = lane >> 4;
    const int n0   = wave << 5;                  // 32-col strip per wave

    f32x4 acc0 = {0.f, 0.f, 0.f, 0.f}, acc1 = acc0;

    const unsigned short* Qp = Qb + ((size_t)bh * CH + c0) * DHEAD;
    const unsigned short* Kp = Kb + (size_t)bh * CH * DHEAD;

    const int qr = tid >> 4, qu = tid & 15;      // Q stage: one unit per thread
    const unsigned qoff = (unsigned)((qr << 8) + (qu << 4)) ^ (((unsigned)qr & 7u) << 4);

    #pragma unroll 1
    for (int chk = 0; chk < 16; ++chk) {
        const int t0 = chk << 7;
        __syncthreads();
        {
            const bf16x8 v = *(const bf16x8*)&Qp[(size_t)qr * DHEAD + t0 + qu * 8];
            *(bf16x8*)(smem + qoff) = v;
        }
        for (int i = tid; i < 2048; i += 256) {  // K: 128 rows x 16 units
            const int r = i >> 4, u = i & 15;
            const bf16x8 v = *(const bf16x8*)&Kp[(size_t)r * DHEAD + t0 + u * 8];
            const unsigned off = 4096u +
                ((unsigned)((r << 8) + (u << 4)) ^ (((unsigned)r & 7u) << 4));
            *(bf16x8*)(smem + off) = v;
        }
        __syncthreads();
        #pragma unroll
        for (int ki = 0; ki < 4; ++ki) {
            const int kcb = (ki * 32 + qd * 8) << 1;     // k byte offset
            const bf16x8 a = *(const bf16x8*)(smem +
                ((unsigned)((lx << 8) + kcb) ^ (((unsigned)lx & 7u) << 4)));
            const int r0 = n0 + lx, r1 = n0 + 16 + lx;
            const bf16x8 b0 = *(const bf16x8*)(smem + 4096u +
                ((unsigned)((r0 << 8) + kcb) ^ (((unsigned)r0 & 7u) << 4)));
            const bf16x8 b1 = *(const bf16x8*)(smem + 4096u +
                ((unsigned)((r1 << 8) + kcb) ^ (((unsigned)r1 & 7u) << 4)));
            acc0 = __builtin_amdgcn_mfma_f32_16x16x32_bf16(a, b0, acc0, 0, 0, 0);
            acc1 = __builtin_amdgcn_mfma_f32_16x16x32_bf16(a, b1, acc1, 0, 0, 0);
        }
    }

    __syncthreads();
    float* Ss = (float*)smem;                    // [16][132] f32, 8448 B
    #pragma unroll
    for (int r = 0; r < 4; ++r) {
        Ss[(qd * 4 + r) * 132 + n0 + lx]      = acc0[r];
        Ss[(qd * 4 + r) * 132 + n0 + 16 + lx] = acc1[r];
    }
    __syncthreads();

    // softmax: 16 threads per row, 8 cols each
    const int rr = tid >> 4;
    const int c8 = (tid & 15) << 3;
    f32x4 v0 = *(const f32x4*)&Ss[rr * 132 + c8];
    f32x4 v1 = *(const f32x4*)&Ss[rr * 132 + c8 + 4];
    const f32x4 sc = {0.0078125f, 0.0078125f, 0.0078125f, 0.0078125f};
    v0 *= sc; v1 *= sc;
    float m = fmaxf(fmaxf(fmaxf(v0[0], v0[1]), fmaxf(v0[2], v0[3])),
                    fmaxf(fmaxf(v1[0], v1[1]), fmaxf(v1[2], v1[3])));
    m = fmaxf(m, __shfl_xor(m, 1));
    m = fmaxf(m, __shfl_xor(m, 2));
    m = fmaxf(m, __shfl_xor(m, 4));
    m = fmaxf(m, __shfl_xor(m, 8));
    float e[8];
    #pragma unroll
    for (int j = 0; j < 4; ++j) {
        e[j]     = __expf(v0[j] - m);
        e[4 + j] = __expf(v1[j] - m);
    }
    float s = 0.f;
    #pragma unroll
    for (int j = 0; j < 8; ++j) s += e[j];
    s += __shfl_xor(s, 1);
    s += __shfl_xor(s, 2);
    s += __shfl_xor(s, 4);
    s += __shfl_xor(s, 8);
    const float inv = 1.f / s;
    bf16x8 h;
    #pragma unroll
    for (int j = 0; j < 8; ++j) h[j] = (short)f2bf(e[j] * inv);
    *(bf16x8*)&Pb[((size_t)bh * CH + c0 + rr) * CH + c8] = h;
}

// ---------------- Kernel 4: A = P V via MFMA, out At[b][p][ci] bf16 ------------
__global__ __launch_bounds__(256) void pv_mfma_kernel(
    const unsigned short* __restrict__ Pb, const unsigned short* __restrict__ Vb,
    unsigned short* __restrict__ At)
{
    const int blk = blockIdx.x;
    const int t0  = (blk & 15) << 7;
    const int bh  = blk >> 4;

    __shared__ __align__(16) char smem[69632];
    unsigned short (*Ps)[136] = (unsigned short(*)[136])smem;            // 34816 B
    unsigned short (*Vs)[136] = (unsigned short(*)[136])(smem + 34816);  // 34816 B
    float (*So)[132] = (float(*)[132])smem;                              // reused

    const int tid  = threadIdx.x;
    const int wave = tid >> 6;
    const int lane = tid & 63;
    const int lx   = lane & 15;
    const int qd   = lane >> 4;
    const int m0   = (wave & 1) * 64;      // c tile
    const int n0   = (wave >> 1) * 64;     // t tile

    const unsigned short* Pp = Pb + (size_t)bh * CH * CH;
    const unsigned short* Vp = Vb + (size_t)bh * CH * DHEAD;

    for (int i = tid; i < 2048; i += 256) {
        const int r  = i >> 4;
        const int cl = (i & 15) << 3;
        *(bf16x8*)&Ps[r][cl] = *(const bf16x8*)&Pp[(size_t)r * CH + cl];
    }
    for (int i = tid; i < 2048; i += 256) {
        const int e   = i & 127;
        const int tc8 = (i >> 7) << 3;
        const bf16x8 vv = *(const bf16x8*)&Vp[(size_t)e * DHEAD + t0 + tc8];
        #pragma unroll
        for (int j = 0; j < 8; ++j) Vs[tc8 + j][e] = (unsigned short)vv[j];
    }
    __syncthreads();

    f32x4 acc[4][4];
    #pragma unroll
    for (int mi = 0; mi < 4; ++mi)
        #pragma unroll
        for (int ni = 0; ni < 4; ++ni) acc[mi][ni] = (f32x4){0.f, 0.f, 0.f, 0.f};

    #pragma unroll
    for (int ki = 0; ki < 4; ++ki) {
        const int kc = ki * 32 + qd * 8;
        bf16x8 a[4], bv[4];
        #pragma unroll
        for (int mi = 0; mi < 4; ++mi)
            a[mi] = *(const bf16x8*)&Ps[m0 + mi * 16 + lx][kc];
        #pragma unroll
        for (int ni = 0; ni < 4; ++ni)
            bv[ni] = *(const bf16x8*)&Vs[n0 + ni * 16 + lx][kc];
        #pragma unroll
        for (int mi = 0; mi < 4; ++mi)
            #pragma unroll
            for (int ni = 0; ni < 4; ++ni)
                acc[mi][ni] = __builtin_amdgcn_mfma_f32_16x16x32_bf16(
                    a[mi], bv[ni], acc[mi][ni], 0, 0, 0);
    }

    __syncthreads();
    #pragma unroll
    for (int mi = 0; mi < 4; ++mi)
        #pragma unroll
        for (int ni = 0; ni < 4; ++ni)
            #pragma unroll
            for (int r = 0; r < 4; ++r)
                So[n0 + ni * 16 + lx][m0 + mi * 16 + qd * 4 + r] = acc[mi][ni][r];
    __syncthreads();

    const int t  = tid >> 1;
    const int ch = (tid & 1) * 64;
    const size_t orow = (((size_t)(bh >> 3) * HWSZ) + (size_t)(bh & 7) * DHEAD + t0 + t) * CH + ch;
    #pragma unroll
    for (int j = 0; j < 8; ++j) {
        const float4 f0 = *(const float4*)&So[t][ch + j * 8];
        const float4 f1 = *(const float4*)&So[t][ch + j * 8 + 4];
        bf16x8 h;
        h[0] = (short)f2bf(f0.x); h[1] = (short)f2bf(f0.y);
        h[2] = (short)f2bf(f0.z); h[3] = (short)f2bf(f0.w);
        h[4] = (short)f2bf(f1.x); h[5] = (short)f2bf(f1.y);
        h[6] = (short)f2bf(f1.z); h[7] = (short)f2bf(f1.w);
        *(bf16x8*)&At[orow + j * 8] = h;
    }
}

// ---------------- Kernel 5a: weight prep wo fp32 -> Wt[tap][co][ci] bf16 ------
__global__ __launch_bounds__(256) void wprep_kernel(
    const float* __restrict__ wo, unsigned short* __restrict__ Wt)
{
    const int i = blockIdx.x * 256 + threadIdx.x;     // 9*128*128 = 147456
    const int tap = i >> 14;
    const int rem = i & 16383;
    const int co  = rem >> 7;
    const int ci  = rem & 127;
    Wt[i] = f2bf(wo[(size_t)(co * CH + ci) * 9 + tap]);
}

// ---------------- Kernel 5b: 3x3 dense conv, 2-row blocks ---------------------
__global__ __launch_bounds__(512, 2) void conv3x3_mfma_kernel(
    const unsigned short* __restrict__ At, const unsigned short* __restrict__ Wt,
    const float* __restrict__ bo, float* __restrict__ out)
{
    __shared__ __align__(16) char smem[163840];   // sA 131072 + sW 2x16384

    const int w    = ((blockIdx.x & 7) << 6) | (blockIdx.x >> 3);
    const int yp   = w & 63;
    const int b    = w >> 6;
    const int y0   = yp << 1;

    const int tid  = threadIdx.x;
    const int wave = tid >> 6;
    const int lane = tid & 63;
    const int lx   = lane & 15;
    const int qd   = lane >> 4;
    const int m0   = (wave & 1) << 6;       // co half
    const int n0   = (wave >> 1) << 6;      // px quarter
    const int rsel = n0 >> 7;               // output row within pair (0/1)
    const int xb   = n0 & 64;               // x base within row

    const int j0 = tid, j1 = tid + 512;     // weight 16B-unit indices (0..1023)
    const int co0 = j0 >> 3, cu0 = j0 & 7;
    const int co1 = j1 >> 3, cu1 = j1 & 7;
    const unsigned swo0 = (unsigned)((co0 * 128 + cu0 * 16) ^ ((co0 & 7) << 4)) + 131072u;
    const unsigned swo1 = (unsigned)((co1 * 128 + cu1 * 16) ^ ((co1 & 7) << 4)) + 131072u;

    float4 nwa = *(const float4*)&Wt[(size_t)co0 * 128 + cu0 * 8];
    float4 nwb = *(const float4*)&Wt[(size_t)co1 * 128 + cu1 * 8];

    const size_t abase = (size_t)b * HWSZ * CH;
    for (int i = tid; i < 8192; i += 512) {
        const int r   = i >> 11;
        const int rem = i & 2047;
        const int xx  = rem >> 4;               // 0..127
        const int u   = rem & 15;
        const int gy  = y0 - 1 + r;
        float4 v = make_float4(0.f, 0.f, 0.f, 0.f);
        if ((unsigned)gy < HH)
            v = *(const float4*)&At[abase + (size_t)gy * WW * CH + xx * CH + u * 8];
        const int xp = xx + 1;
        const unsigned off = (unsigned)((r << 15) + (xx << 8) + (u << 4))
                           ^ (((unsigned)xp & 7u) << 4);
        *(float4*)(smem + off) = v;
    }
    *(float4*)(smem + swo0) = nwa;
    *(float4*)(smem + swo1) = nwb;
    nwa = *(const float4*)&Wt[(size_t)co0 * 128 + 64 + cu0 * 8];
    nwb = *(const float4*)&Wt[(size_t)co1 * 128 + 64 + cu1 * 8];

    f32x4 acc[4][4];
    #pragma unroll
    for (int mi = 0; mi < 4; ++mi) {
        f32x4 bv;
        #pragma unroll
        for (int r = 0; r < 4; ++r) bv[r] = bo[m0 + mi * 16 + qd * 4 + r];
        #pragma unroll
        for (int ni = 0; ni < 4; ++ni) acc[mi][ni] = bv;
    }

    __syncthreads();

    #pragma unroll 1
    for (int s = 0; s < 18; ++s) {
        const int tap = s >> 1;
        const int dy  = (tap * 11) >> 5;        // tap/3
        const int txc = tap - dy * 3;           // tap%3
        const int kh  = s & 1;
        const int ra  = rsel + dy;
        const unsigned wbase = 131072u + (unsigned)(s & 1) * 16384u;

        #pragma unroll
        for (int ks = 0; ks < 2; ++ks) {
            const int wkb = ks * 64 + qd * 16;            // ci-byte in sW slice
            const int akb = kh * 128 + ks * 64 + qd * 16; // ci-byte in sA row
            bf16x8 a[4], bfr[4];
            #pragma unroll
            for (int mi = 0; mi < 4; ++mi) {
                const int co = m0 + mi * 16 + lx;
                a[mi] = *(const bf16x8*)(smem + wbase +
                        (unsigned)((co * 128 + wkb) ^ ((co & 7) << 4)));
            }
            #pragma unroll
            for (int ni = 0; ni < 4; ++ni) {
                const int xp = xb + ni * 16 + lx + txc;   // 0..129
                const bool z = (unsigned)(xp - 1) >= 128u;
                const int xpc = z ? 1 : xp;
                const unsigned off = (unsigned)((ra << 15) + ((xpc - 1) << 8) + akb)
                                   ^ (((unsigned)xpc & 7u) << 4);
                bfr[ni] = *(const bf16x8*)(smem + off);
                if (z) bfr[ni] = (bf16x8){0, 0, 0, 0, 0, 0, 0, 0};
            }
            #pragma unroll
            for (int mi = 0; mi < 4; ++mi)
                #pragma unroll
                for (int ni = 0; ni < 4; ++ni)
                    acc[mi][ni] = __builtin_amdgcn_mfma_f32_16x16x32_bf16(
                        a[mi], bfr[ni], acc[mi][ni], 0, 0, 0);
        }
        if (s < 17) {
            const unsigned nb = 131072u + (unsigned)((s + 1) & 1) * 16384u;
            *(float4*)(smem + (swo0 - 131072u) + nb) = nwa;
            *(float4*)(smem + (swo1 - 131072u) + nb) = nwb;
            if (s < 16) {
                const int s2 = s + 2;
                const size_t gb = (size_t)(s2 >> 1) * 16384 + (s2 & 1) * 64;
                nwa = *(const float4*)&Wt[gb + co0 * 128 + cu0 * 8];
                nwb = *(const float4*)&Wt[gb + co1 * 128 + cu1 * 8];
            }
        }
        __syncthreads();
    }

    const int gy = y0 + rsel;
    const size_t obase = (size_t)b * CH * HWSZ + (size_t)gy * WW + xb;
    #pragma unroll
    for (int mi = 0; mi < 4; ++mi) {
        #pragma unroll
        for (int r = 0; r < 4; ++r) {
            const int co = m0 + mi * 16 + qd * 4 + r;
            float* orow = out + obase + (size_t)co * HWSZ;
            #pragma unroll
            for (int ni = 0; ni < 4; ++ni)
                orow[ni * 16 + lx] = acc[mi][ni][r];
        }
    }
}

extern "C" void kernel_launch(void* const* d_in, const int* in_sizes, int n_in,
                              void* d_out, int out_size, void* d_ws, size_t ws_size,
                              hipStream_t stream)
{
    const float* x  = (const float*)d_in[0];
    const float* wq = (const float*)d_in[1];
    const float* bq = (const float*)d_in[2];
    const float* wk = (const float*)d_in[3];
    const float* bk = (const float*)d_in[4];
    const float* wv = (const float*)d_in[5];
    const float* bv = (const float*)d_in[6];
    const float* wo = (const float*)d_in[7];
    const float* bo = (const float*)d_in[8];

    char* ws = (char*)d_ws;
    unsigned short* Qb    = (unsigned short*)(ws);                        // 32 MiB
    unsigned short* Kb    = (unsigned short*)(ws + (size_t)33554432);     // 32 MiB
    unsigned short* Vb    = (unsigned short*)(ws + (size_t)67108864);     // 32 MiB
    unsigned short* Pb    = (unsigned short*)(ws + (size_t)134217728);    // 2 MiB
    unsigned short* At    = (unsigned short*)(ws + (size_t)136314880);    // 32 MiB
    unsigned short* Wt    = (unsigned short*)(ws + (size_t)169869312);    // 288 KiB
    _Float16*       Tp    = (_Float16*)      (ws + (size_t)100663296);    // 3.5 MiB

    toeplitz_prep_kernel<<<864, 256, 0, stream>>>(wq, wk, wv, Tp);
    dwconv_qkv_mfma_kernel<<<BATCH * CH, 256, 0, stream>>>(x, bq, bk, bv, Tp, Qb, Kb, Vb);
    wprep_kernel<<<576, 256, 0, stream>>>(wo, Wt);
    qks_kernel<<<512, 256, 0, stream>>>(Qb, Kb, Pb);
    pv_mfma_kernel<<<64 * 16, 256, 0, stream>>>(Pb, Vb, At);
    conv3x3_mfma_kernel<<<BATCH * 64, 512, 0, stream>>>(At, Wt, bo, (float*)d_out);
}